// Round 8
// baseline (191.020 us; speedup 1.0000x reference)
//
#include <hip/hip_runtime.h>
#include <hip/hip_bf16.h>

// ---------------------------------------------------------------------------
// DimNet via bf16 MFMA implicit GEMM, K-split wave pairs.
//   Pn  = padded input  NHWC bf16 [2][104][104][32]
//   Bn  = relu(conv2a)  NHWC bf16 [2][100][100][192] (g' = uv*20+mc, MFMA-made)
//   Wp  = packed weights [231 steps][ocb7][frag4][lane64][8] bf16
// conv_mfma: 256 thr / 4 waves; block = 256px(8x32) x 64oc. Wave pair
//   (2p,2p+1) shares tile p = 128px(4x32) x 64oc (acc[8][4]); each wave does
//   HALF the taps; p2 halves combined via LDS (f32) before relu, p1 at end.
//   Halo single-buffered (36.9KB) + 32KB exchange -> 2 blocks/CU, 2 waves/SIMD.
// ---------------------------------------------------------------------------

typedef __attribute__((ext_vector_type(8))) unsigned short ushort8;
typedef __attribute__((ext_vector_type(8))) __bf16 bf16x8;
typedef __attribute__((ext_vector_type(4))) float f32x4;

#define NB 2
#define HSLOT 576          // cells per k-slot (16 rows x 36 cols)
#define WST 14336          // ushorts per step in packed weights (7*4*64*8)
#define NWA (6 * 25 * 7 * 4 * 64 * 8)   // 2,150,400
#define NWB (81 * 7 * 4 * 64 * 8)       // 1,161,216

static __device__ __forceinline__ unsigned short f2bf(float f) {
    __hip_bfloat16 h = __float2bfloat16(f);
    return *reinterpret_cast<unsigned short*>(&h);
}
static __device__ __forceinline__ void gload16(const unsigned short* g, unsigned short* l) {
    __builtin_amdgcn_global_load_lds(
        (const __attribute__((address_space(1))) unsigned int*)(const void*)g,
        (__attribute__((address_space(3))) unsigned int*)(void*)l, 16, 0, 0);
}

// ---------------- pad: NHWC bf16 ----------------
__global__ __launch_bounds__(256) void pad_kernel(const float* __restrict__ pic,
                                                  unsigned short* __restrict__ Pn) {
    int idx = blockIdx.x * 256 + threadIdx.x;
    if (idx >= NB * 104 * 104) return;
    int x = idx % 104;
    int y = (idx / 104) % 104;
    int b = idx / (104 * 104);
    unsigned short vals[32];
    bool inter = (y >= 4 && y < 100 && x >= 4 && x < 100);
#pragma unroll
    for (int c = 0; c < 25; ++c) {
        float v = inter ? pic[((b * 25 + c) * 96 + (y - 4)) * 96 + (x - 4)] : 0.5f;
        vals[c] = f2bf(v);
    }
#pragma unroll
    for (int c = 25; c < 32; ++c) vals[c] = 0;
    ushort8* dst = (ushort8*)(Pn + idx * 32);
#pragma unroll
    for (int j = 0; j < 4; ++j) dst[j] = *(ushort8*)&vals[j * 8];
}

// ---------------- weight prep: 8 outputs/thread, coalesced 16B writes ----------------
__global__ __launch_bounds__(256) void prep_w_kernel(const float* __restrict__ w2b,
                                                     const float* __restrict__ w1,
                                                     unsigned short* __restrict__ Wp) {
    int t = blockIdx.x * 256 + threadIdx.x;
    const int NW8 = (NWA + NWB) / 8;
    if (t >= NW8) return;
    int base = t * 8;
    unsigned short v8[8];
    if (base < NWA) {
        int lane = (base >> 3) & 63, n = (base >> 9) & 3;
        int r = base >> 11;
        int ocb = r % 7; r /= 7;
        int tap = r % 25; int cc = r / 25;
        int oc = ocb * 64 + n * 16 + (lane & 15);
        int kb = cc * 32 + (lane >> 4) * 8;
#pragma unroll
        for (int e = 0; e < 8; ++e) {
            int k = kb + e;
            float v = 0.f;
            if (oc < 400 && k < 180) {
                int mc = k % 20, uv = k / 20;        // g' = uv*20 + mc
                v = w2b[oc * 4500 + (mc * 9 + uv) * 25 + tap];
            }
            v8[e] = f2bf(v);
        }
    } else {
        int kx = base - NWA;
        int lane = (kx >> 3) & 63, n = (kx >> 9) & 3;
        int r = kx >> 11;
        int ocb = r % 7; int tp = r / 7;             // visit order 0..80
        int dy, dx;
        if (tp < 45) { dy = tp / 5; dx = tp % 5; }
        else { int u = tp - 45; dy = u >> 2; dx = 5 + (u & 3); }
        int oc = ocb * 64 + n * 16 + (lane & 15);
        int cb = (lane >> 4) * 8;
#pragma unroll
        for (int e = 0; e < 8; ++e) {
            int c = cb + e;
            float v = (oc < 400 && c < 25) ? w1[oc * 2025 + c * 81 + (dy * 9 + dx)] : 0.f;
            v8[e] = f2bf(v);
        }
    }
    *(ushort8*)(Wp + base) = *(ushort8*)v8;
}

// ---------------- conv2a via MFMA (unchanged from round 7) ----------------
#define MFMA16(A0, A1, A2, A3, B0, B1, B2, B3)                                          \
    {                                                                                   \
        __builtin_amdgcn_s_setprio(1);                                                  \
        acc[0][0] = __builtin_amdgcn_mfma_f32_16x16x32_bf16(A0, B0, acc[0][0], 0, 0, 0);\
        acc[0][1] = __builtin_amdgcn_mfma_f32_16x16x32_bf16(A0, B1, acc[0][1], 0, 0, 0);\
        acc[0][2] = __builtin_amdgcn_mfma_f32_16x16x32_bf16(A0, B2, acc[0][2], 0, 0, 0);\
        acc[0][3] = __builtin_amdgcn_mfma_f32_16x16x32_bf16(A0, B3, acc[0][3], 0, 0, 0);\
        acc[1][0] = __builtin_amdgcn_mfma_f32_16x16x32_bf16(A1, B0, acc[1][0], 0, 0, 0);\
        acc[1][1] = __builtin_amdgcn_mfma_f32_16x16x32_bf16(A1, B1, acc[1][1], 0, 0, 0);\
        acc[1][2] = __builtin_amdgcn_mfma_f32_16x16x32_bf16(A1, B2, acc[1][2], 0, 0, 0);\
        acc[1][3] = __builtin_amdgcn_mfma_f32_16x16x32_bf16(A1, B3, acc[1][3], 0, 0, 0);\
        acc[2][0] = __builtin_amdgcn_mfma_f32_16x16x32_bf16(A2, B0, acc[2][0], 0, 0, 0);\
        acc[2][1] = __builtin_amdgcn_mfma_f32_16x16x32_bf16(A2, B1, acc[2][1], 0, 0, 0);\
        acc[2][2] = __builtin_amdgcn_mfma_f32_16x16x32_bf16(A2, B2, acc[2][2], 0, 0, 0);\
        acc[2][3] = __builtin_amdgcn_mfma_f32_16x16x32_bf16(A2, B3, acc[2][3], 0, 0, 0);\
        acc[3][0] = __builtin_amdgcn_mfma_f32_16x16x32_bf16(A3, B0, acc[3][0], 0, 0, 0);\
        acc[3][1] = __builtin_amdgcn_mfma_f32_16x16x32_bf16(A3, B1, acc[3][1], 0, 0, 0);\
        acc[3][2] = __builtin_amdgcn_mfma_f32_16x16x32_bf16(A3, B2, acc[3][2], 0, 0, 0);\
        acc[3][3] = __builtin_amdgcn_mfma_f32_16x16x32_bf16(A3, B3, acc[3][3], 0, 0, 0);\
        __builtin_amdgcn_s_setprio(0);                                                  \
    }

__global__ __launch_bounds__(256) void conv2a_mfma_kernel(
    const unsigned short* __restrict__ Pn, const float* __restrict__ w2a,
    const float* __restrict__ b2a, unsigned short* __restrict__ Bn) {
    __shared__ __align__(16) unsigned short sWc[25 * 2048];
    __shared__ __align__(16) unsigned short sHalo[4 * 448 * 8];

    const int tid  = threadIdx.x;
    const int lane = tid & 63, w = tid >> 6;
    const int l15  = lane & 15, lhi = lane >> 4;
    const int gx0  = blockIdx.x;
    const int b    = gx0 / 52, t52 = gx0 % 52;
    const int ty0  = (t52 >> 2) * 8;
    const int tx0  = (t52 & 3) * 32;
    const int ocB  = blockIdx.y;

    {
        int oc = ocB * 64 + w * 16 + (lane & 15);
        int kb = (lane >> 4) * 8;
        int uv = oc / 20;
        int mc = oc - uv * 20;
        int u = uv / 3, v = uv - (uv / 3) * 3;
        const float* wb[8];
#pragma unroll
        for (int e = 0; e < 8; ++e) {
            int k  = kb + e;
            int c1 = k / 5, c2 = k - (k / 5) * 5;
            int da1 = c1 - u, da2 = c2 - v;
            bool valid = (oc < 180) && ((unsigned)da1 < 3u) && ((unsigned)da2 < 3u);
            wb[e] = valid ? (w2a + mc * 225 + (da1 * 3 + da2) * 25) : (const float*)0;
        }
#pragma unroll
        for (int tap = 0; tap < 25; ++tap) {
            unsigned short fr[8];
#pragma unroll
            for (int e = 0; e < 8; ++e) fr[e] = wb[e] ? f2bf(wb[e][tap]) : (unsigned short)0;
            *(ushort8*)&sWc[tap * 2048 + tid * 8] = *(ushort8*)fr;
        }
    }

    for (int L2 = 0; L2 < 7; ++L2) {
        int p = L2 * 64 + lane;
        if (p >= 432) p = 0;
        int hy = (p * 58255) >> 21, hx = p - hy * 36;
        int gy = ty0 + hy; gy = gy > 103 ? 103 : gy;
        int gx = tx0 + hx; gx = gx > 103 ? 103 : gx;
        gload16(Pn + ((size_t)((b * 104 + gy) * 104 + gx)) * 32 + w * 8,
                &sHalo[(w * 448 + L2 * 64) * 8]);
    }
    float bs[4];
#pragma unroll
    for (int n = 0; n < 4; ++n) {
        int oc = ocB * 64 + n * 16 + l15;
        bs[n] = (oc < 180) ? b2a[oc % 20] : 0.f;
    }
    __syncthreads();

    const unsigned short* hb = &sHalo[(lhi * 448 + w * 72 + l15) * 8];
    const unsigned short* wc = &sWc[lane * 8];

    f32x4 acc[4][4] = {};
    bf16x8 a0 = *(const bf16x8*)(hb), a1 = *(const bf16x8*)(hb + 128);
    bf16x8 a2 = *(const bf16x8*)(hb + 288), a3 = *(const bf16x8*)(hb + 416);
    bf16x8 c0 = *(const bf16x8*)(wc), c1 = *(const bf16x8*)(wc + 512);
    bf16x8 c2 = *(const bf16x8*)(wc + 1024), c3 = *(const bf16x8*)(wc + 1536);
    bf16x8 q0, q1, q2, q3, n0, n1, n2, n3;
#pragma unroll
    for (int t = 0; t < 25; ++t) {
        if (t < 24) {
            const int u = (((t + 1) / 5) * 36 + ((t + 1) % 5)) * 8;
            q0 = *(const bf16x8*)(hb + u);
            q1 = *(const bf16x8*)(hb + u + 128);
            q2 = *(const bf16x8*)(hb + u + 288);
            q3 = *(const bf16x8*)(hb + u + 416);
            const unsigned short* wn = wc + (t + 1) * 2048;
            n0 = *(const bf16x8*)(wn);
            n1 = *(const bf16x8*)(wn + 512);
            n2 = *(const bf16x8*)(wn + 1024);
            n3 = *(const bf16x8*)(wn + 1536);
        }
        MFMA16(a0, a1, a2, a3, c0, c1, c2, c3);
        if (t < 24) { a0 = q0; a1 = q1; a2 = q2; a3 = q3;
                      c0 = n0; c1 = n1; c2 = n2; c3 = n3; }
    }

#pragma unroll
    for (int n = 0; n < 4; ++n) {
        int oc = ocB * 64 + n * 16 + l15;
#pragma unroll
        for (int m = 0; m < 4; ++m) {
            int y = ty0 + w * 2 + (m >> 1);
            if (y >= 100) continue;
            int x0 = tx0 + (m & 1) * 16 + lhi * 4;
#pragma unroll
            for (int i = 0; i < 4; ++i) {
                int x = x0 + i;
                if (x >= 100) continue;
                Bn[((size_t)((b * 100 + y) * 100 + x)) * 192 + oc] =
                    f2bf(fmaxf(acc[m][n][i] + bs[n], 0.f));
            }
        }
    }
}

// ---------------- main MFMA conv: K-split wave pairs, m=8 ----------------
__global__ __launch_bounds__(256, 2) void conv_mfma_kernel(
    const unsigned short* __restrict__ Pn, const unsigned short* __restrict__ Bn,
    const unsigned short* __restrict__ Wp, const float* __restrict__ b1,
    const float* __restrict__ b2b, float* __restrict__ out) {
    __shared__ __align__(16) unsigned short sHalo[4 * HSLOT * 8];  // 36,864 B
    __shared__ __align__(16) float sExch[2][4096];                 // 32,768 B

    const int tid   = threadIdx.x;
    const int lane  = tid & 63, w = tid >> 6;
    const int l15   = lane & 15, lhi = lane >> 4;
    const int pairI = w >> 1;   // tile: rows pairI*4 .. +3
    const int kh    = w & 1;    // tap-half
    const int ocB   = blockIdx.y;
    const int pb    = blockIdx.x;
    const int b     = pb / 36;
    const int t36   = pb % 36;
    const int ty0   = (t36 / 3) * 8;
    const int tx0   = (t36 % 3) * 32;

    const int vA = (lhi * HSLOT + pairI * 144 + l15) * 8;

    auto stageA = [&](int cc) {  // Bn halo 12x36, wave w stages k-slot w
        for (int L2 = 0; L2 < 7; ++L2) {
            int p = L2 * 64 + lane;
            if (p >= 432) p = 0;
            int hy = (p * 58255) >> 21, hx = p - hy * 36;
            gload16(Bn + ((size_t)((b * 100 + ty0 + hy) * 100 + tx0 + hx)) * 192 +
                        cc * 32 + w * 8,
                    &sHalo[(w * HSLOT + L2 * 64) * 8]);
        }
    };
    auto stageB = [&](int seg) {  // Pn halo 16x36 (seg7 origin +5 cols)
        int cx = tx0 + (seg == 7 ? 5 : 0);
        for (int L2 = 0; L2 < 9; ++L2) {
            int p = L2 * 64 + lane;
            int hy = (p * 58255) >> 21, hx = p - hy * 36;
            int gx = cx + hx;
            gx = gx > 103 ? 103 : gx;
            gload16(Pn + ((size_t)((b * 104 + ty0 + hy) * 104 + gx)) * 32 + w * 8,
                    &sHalo[(w * HSLOT + L2 * 64) * 8]);
        }
    };

    float bb2[4], bb1[4];
#pragma unroll
    for (int n = 0; n < 4; ++n) {
        int oc  = ocB * 64 + n * 16 + l15;
        int occ = oc < 400 ? oc : 399;
        bb2[n] = b2b[occ];
        bb1[n] = b1[occ];
    }

    f32x4 acc[8][4] = {};

    constexpr int AOFF[8] = {0, 128, 288, 416, 576, 704, 864, 992};

    auto tap = [&](const unsigned short* ha, const unsigned short* wp) {
        bf16x8 af[8], cf[4];
#pragma unroll
        for (int m = 0; m < 8; ++m) af[m] = *(const bf16x8*)(ha + AOFF[m]);
#pragma unroll
        for (int n = 0; n < 4; ++n) cf[n] = *(const bf16x8*)(wp + n * 512);
        __builtin_amdgcn_s_setprio(1);
#pragma unroll
        for (int m = 0; m < 8; ++m)
#pragma unroll
            for (int n = 0; n < 4; ++n)
                acc[m][n] = __builtin_amdgcn_mfma_f32_16x16x32_bf16(af[m], cf[n],
                                                                    acc[m][n], 0, 0, 0);
        __builtin_amdgcn_s_setprio(0);
    };

    auto runseg = [&](int sbase, int kb, int nt, bool b2m) {
        const unsigned short* wp = Wp + (size_t)(sbase + kb) * WST + ocB * 2048 + lane * 8;
#pragma unroll
        for (int t = 0; t < nt; ++t) {
            int k = kb + t;
            int hoff = b2m ? (((k >> 2) * 36 + (k & 3)) * 8)
                           : (((k / 5) * 36 + (k % 5)) * 8);
            tap(&sHalo[vA + hoff], wp);
            wp += WST;
        }
    };

    auto exwrite = [&](int h) {
#pragma unroll
        for (int mm = 0; mm < 4; ++mm)
#pragma unroll
            for (int n = 0; n < 4; ++n)
#pragma unroll
                for (int i = 0; i < 4; ++i)
                    sExch[pairI][(mm * 16 + n * 4 + i) * 64 + lane] = acc[h * 4 + mm][n][i];
    };
    auto exread = [&](int h) {
#pragma unroll
        for (int mm = 0; mm < 4; ++mm)
#pragma unroll
            for (int n = 0; n < 4; ++n)
#pragma unroll
                for (int i = 0; i < 4; ++i)
                    acc[h * 4 + mm][n][i] += sExch[pairI][(mm * 16 + n * 4 + i) * 64 + lane];
    };

    // -------- phase A: 6 segments x 25 taps (split 13/12) --------
    stageA(0);
    __syncthreads();
    for (int cc = 0; cc < 6; ++cc) {
        if (kh) runseg(cc * 25, 13, 12, false);
        else    runseg(cc * 25,  0, 13, false);
        __syncthreads();
        if (cc < 5) {
            stageA(cc + 1);
            __syncthreads();
        }
    }

    // -------- mid: combine p2 halves, relu (odd keeps X, even zeroes) --------
    stageB(6);
#pragma unroll
    for (int h = 0; h < 2; ++h) {
        if (!kh) exwrite(h);
        __syncthreads();
        if (kh) exread(h);
        __syncthreads();
    }
    if (kh) {
#pragma unroll
        for (int m = 0; m < 8; ++m)
#pragma unroll
            for (int n = 0; n < 4; ++n)
#pragma unroll
                for (int i = 0; i < 4; ++i)
                    acc[m][n][i] = fmaxf(acc[m][n][i] + bb2[n], 0.f);
    } else {
#pragma unroll
        for (int m = 0; m < 8; ++m)
#pragma unroll
            for (int n = 0; n < 4; ++n)
                acc[m][n] = f32x4{0.f, 0.f, 0.f, 0.f};
    }

    // -------- phase B1: 45 taps (dy0..8, dx0..4), split 23/22 --------
    if (kh) runseg(150, 23, 22, false);
    else    runseg(150,  0, 23, false);
    __syncthreads();
    stageB(7);
    __syncthreads();

    // -------- phase B2: 36 taps (dy0..8, dx5..8), split 18/18 --------
    if (kh) runseg(195, 18, 18, true);
    else    runseg(195,  0, 18, true);

    // -------- final: combine p1 halves into odd waves, store --------
#pragma unroll
    for (int h = 0; h < 2; ++h) {
        if (!kh) exwrite(h);
        __syncthreads();
        if (kh) exread(h);
        if (h == 0) __syncthreads();
    }
    if (kh) {
#pragma unroll
        for (int n = 0; n < 4; ++n) {
            int oc = ocB * 64 + n * 16 + l15;
            if (oc >= 400) continue;
            float bv = bb1[n];
            int c25 = oc >> 4, r1 = (oc >> 2) & 3, r2 = oc & 3;
#pragma unroll
            for (int m = 0; m < 8; ++m) {
                int y  = ty0 + pairI * 4 + (m >> 1);
                int x0 = tx0 + (m & 1) * 16 + lhi * 4;
#pragma unroll
                for (int i = 0; i < 4; ++i) {
                    out[((size_t)(b * 25 + c25) * 384 + y * 4 + r1) * 384 + (x0 + i) * 4 + r2] =
                        (acc[m][n][i] + bv) * 0.5f;
                }
            }
        }
    }
}

extern "C" void kernel_launch(void* const* d_in, const int* in_sizes, int n_in,
                              void* d_out, int out_size, void* d_ws, size_t ws_size,
                              hipStream_t stream) {
    const float* pic = (const float*)d_in[0];
    const float* w1  = (const float*)d_in[1];
    const float* b1  = (const float*)d_in[2];
    const float* w2a = (const float*)d_in[3];
    const float* b2a = (const float*)d_in[4];
    const float* w2b = (const float*)d_in[5];
    const float* b2b = (const float*)d_in[6];
    float* out = (float*)d_out;

    char* ws = (char*)d_ws;
    unsigned short* Pn = (unsigned short*)(ws);             // 1,384,448 B
    unsigned short* Bn = (unsigned short*)(ws + 1384448);   // 7,680,000 B
    unsigned short* Wp = (unsigned short*)(ws + 9064448);   // 6,623,232 B

    pad_kernel<<<(NB * 104 * 104 + 255) / 256, 256, 0, stream>>>(pic, Pn);
    prep_w_kernel<<<(((NWA + NWB) / 8) + 255) / 256, 256, 0, stream>>>(w2b, w1, Wp);
    conv2a_mfma_kernel<<<dim3(104, 3), 256, 0, stream>>>(Pn, w2a, b2a, Bn);
    conv_mfma_kernel<<<dim3(72, 7), 256, 0, stream>>>(Pn, Bn, Wp, b1, b2b, out);
}

// Round 9
// 189.023 us; speedup vs baseline: 1.0106x; 1.0106x over previous
//
#include <hip/hip_runtime.h>
#include <hip/hip_bf16.h>

// ---------------------------------------------------------------------------
// DimNet via bf16 MFMA implicit GEMM, thin-oc tiles for occupancy.
//   Pn  = padded input  NHWC bf16 [2][104][104][32]
//   Bn  = relu(conv2a)  NHWC bf16 [2][100][100][192] (g' = uv*20+mc, MFMA-made)
//   Wp  = packed weights [231 steps][ocb13][frag2][lane64][8] bf16 (oc pad 416)
// conv_mfma: 256 thr / 4 waves; block = 256px(8x32) x 32oc; wave w owns rows
//   2w..2w+1 (64px), acc[4][2]/thread. Halo-stationary A (single buffer,
//   8 segments, barriers only at swaps); weights direct global (L1/L2).
//   Grid 13x72 = 936 blocks (~3.7 blocks/CU) -> ~3.7 waves/SIMD.
// ---------------------------------------------------------------------------

typedef __attribute__((ext_vector_type(8))) unsigned short ushort8;
typedef __attribute__((ext_vector_type(8))) __bf16 bf16x8;
typedef __attribute__((ext_vector_type(4))) float f32x4;

#define NB 2
#define HSLOT 576            // cells per k-slot (16 rows x 36 cols)
#define WSTP 13312           // ushorts per step: 13 ocb * 2 frag * 64 * 8
#define NWTOT (231 * WSTP)   // 3,075,072 ushorts = 6,150,144 B

static __device__ __forceinline__ unsigned short f2bf(float f) {
    __hip_bfloat16 h = __float2bfloat16(f);
    return *reinterpret_cast<unsigned short*>(&h);
}
static __device__ __forceinline__ void gload16(const unsigned short* g, unsigned short* l) {
    __builtin_amdgcn_global_load_lds(
        (const __attribute__((address_space(1))) unsigned int*)(const void*)g,
        (__attribute__((address_space(3))) unsigned int*)(void*)l, 16, 0, 0);
}

// ---------------- pad: NHWC bf16 ----------------
__global__ __launch_bounds__(256) void pad_kernel(const float* __restrict__ pic,
                                                  unsigned short* __restrict__ Pn) {
    int idx = blockIdx.x * 256 + threadIdx.x;
    if (idx >= NB * 104 * 104) return;
    int x = idx % 104;
    int y = (idx / 104) % 104;
    int b = idx / (104 * 104);
    unsigned short vals[32];
    bool inter = (y >= 4 && y < 100 && x >= 4 && x < 100);
#pragma unroll
    for (int c = 0; c < 25; ++c) {
        float v = inter ? pic[((b * 25 + c) * 96 + (y - 4)) * 96 + (x - 4)] : 0.5f;
        vals[c] = f2bf(v);
    }
#pragma unroll
    for (int c = 25; c < 32; ++c) vals[c] = 0;
    ushort8* dst = (ushort8*)(Pn + idx * 32);
#pragma unroll
    for (int j = 0; j < 4; ++j) dst[j] = *(ushort8*)&vals[j * 8];
}

// ---------------- weight prep: [step][ocb13][frag2][lane][8], 8/thread ----------------
__global__ __launch_bounds__(256) void prep_w_kernel(const float* __restrict__ w2b,
                                                     const float* __restrict__ w1,
                                                     unsigned short* __restrict__ Wp) {
    int t = blockIdx.x * 256 + threadIdx.x;
    if (t >= NWTOT / 8) return;
    int lane = t & 63;
    int r    = t >> 6;
    int n    = r & 1;  r >>= 1;
    int ocb  = r % 13;
    int step = r / 13;
    int oc   = ocb * 32 + n * 16 + (lane & 15);
    int kb   = (lane >> 4) * 8;
    unsigned short v8[8];
    if (step < 150) {
        int cc = step / 25, tap = step % 25;
#pragma unroll
        for (int e = 0; e < 8; ++e) {
            int k = cc * 32 + kb + e;
            float v = 0.f;
            if (oc < 400 && k < 180) {
                int mc = k % 20, uv = k / 20;        // g' = uv*20 + mc
                v = w2b[oc * 4500 + (mc * 9 + uv) * 25 + tap];
            }
            v8[e] = f2bf(v);
        }
    } else {
        int tp = step - 150;                         // visit order 0..80
        int dy, dx;
        if (tp < 45) { dy = tp / 5; dx = tp % 5; }
        else { int u = tp - 45; dy = u >> 2; dx = 5 + (u & 3); }
#pragma unroll
        for (int e = 0; e < 8; ++e) {
            int c = kb + e;
            float v = (oc < 400 && c < 25) ? w1[oc * 2025 + c * 81 + (dy * 9 + dx)] : 0.f;
            v8[e] = f2bf(v);
        }
    }
    *(ushort8*)(Wp + t * 8) = *(ushort8*)v8;
}

// ---------------- conv2a via MFMA (unchanged, known-good) ----------------
#define MFMA16(A0, A1, A2, A3, B0, B1, B2, B3)                                          \
    {                                                                                   \
        __builtin_amdgcn_s_setprio(1);                                                  \
        acc[0][0] = __builtin_amdgcn_mfma_f32_16x16x32_bf16(A0, B0, acc[0][0], 0, 0, 0);\
        acc[0][1] = __builtin_amdgcn_mfma_f32_16x16x32_bf16(A0, B1, acc[0][1], 0, 0, 0);\
        acc[0][2] = __builtin_amdgcn_mfma_f32_16x16x32_bf16(A0, B2, acc[0][2], 0, 0, 0);\
        acc[0][3] = __builtin_amdgcn_mfma_f32_16x16x32_bf16(A0, B3, acc[0][3], 0, 0, 0);\
        acc[1][0] = __builtin_amdgcn_mfma_f32_16x16x32_bf16(A1, B0, acc[1][0], 0, 0, 0);\
        acc[1][1] = __builtin_amdgcn_mfma_f32_16x16x32_bf16(A1, B1, acc[1][1], 0, 0, 0);\
        acc[1][2] = __builtin_amdgcn_mfma_f32_16x16x32_bf16(A1, B2, acc[1][2], 0, 0, 0);\
        acc[1][3] = __builtin_amdgcn_mfma_f32_16x16x32_bf16(A1, B3, acc[1][3], 0, 0, 0);\
        acc[2][0] = __builtin_amdgcn_mfma_f32_16x16x32_bf16(A2, B0, acc[2][0], 0, 0, 0);\
        acc[2][1] = __builtin_amdgcn_mfma_f32_16x16x32_bf16(A2, B1, acc[2][1], 0, 0, 0);\
        acc[2][2] = __builtin_amdgcn_mfma_f32_16x16x32_bf16(A2, B2, acc[2][2], 0, 0, 0);\
        acc[2][3] = __builtin_amdgcn_mfma_f32_16x16x32_bf16(A2, B3, acc[2][3], 0, 0, 0);\
        acc[3][0] = __builtin_amdgcn_mfma_f32_16x16x32_bf16(A3, B0, acc[3][0], 0, 0, 0);\
        acc[3][1] = __builtin_amdgcn_mfma_f32_16x16x32_bf16(A3, B1, acc[3][1], 0, 0, 0);\
        acc[3][2] = __builtin_amdgcn_mfma_f32_16x16x32_bf16(A3, B2, acc[3][2], 0, 0, 0);\
        acc[3][3] = __builtin_amdgcn_mfma_f32_16x16x32_bf16(A3, B3, acc[3][3], 0, 0, 0);\
        __builtin_amdgcn_s_setprio(0);                                                  \
    }

__global__ __launch_bounds__(256) void conv2a_mfma_kernel(
    const unsigned short* __restrict__ Pn, const float* __restrict__ w2a,
    const float* __restrict__ b2a, unsigned short* __restrict__ Bn) {
    __shared__ __align__(16) unsigned short sWc[25 * 2048];
    __shared__ __align__(16) unsigned short sHalo[4 * 448 * 8];

    const int tid  = threadIdx.x;
    const int lane = tid & 63, w = tid >> 6;
    const int l15  = lane & 15, lhi = lane >> 4;
    const int gx0  = blockIdx.x;
    const int b    = gx0 / 52, t52 = gx0 % 52;
    const int ty0  = (t52 >> 2) * 8;
    const int tx0  = (t52 & 3) * 32;
    const int ocB  = blockIdx.y;

    {
        int oc = ocB * 64 + w * 16 + (lane & 15);
        int kb = (lane >> 4) * 8;
        int uv = oc / 20;
        int mc = oc - uv * 20;
        int u = uv / 3, v = uv - (uv / 3) * 3;
        const float* wb[8];
#pragma unroll
        for (int e = 0; e < 8; ++e) {
            int k  = kb + e;
            int c1 = k / 5, c2 = k - (k / 5) * 5;
            int da1 = c1 - u, da2 = c2 - v;
            bool valid = (oc < 180) && ((unsigned)da1 < 3u) && ((unsigned)da2 < 3u);
            wb[e] = valid ? (w2a + mc * 225 + (da1 * 3 + da2) * 25) : (const float*)0;
        }
#pragma unroll
        for (int tap = 0; tap < 25; ++tap) {
            unsigned short fr[8];
#pragma unroll
            for (int e = 0; e < 8; ++e) fr[e] = wb[e] ? f2bf(wb[e][tap]) : (unsigned short)0;
            *(ushort8*)&sWc[tap * 2048 + tid * 8] = *(ushort8*)fr;
        }
    }

    for (int L2 = 0; L2 < 7; ++L2) {
        int p = L2 * 64 + lane;
        if (p >= 432) p = 0;
        int hy = (p * 58255) >> 21, hx = p - hy * 36;
        int gy = ty0 + hy; gy = gy > 103 ? 103 : gy;
        int gx = tx0 + hx; gx = gx > 103 ? 103 : gx;
        gload16(Pn + ((size_t)((b * 104 + gy) * 104 + gx)) * 32 + w * 8,
                &sHalo[(w * 448 + L2 * 64) * 8]);
    }
    float bs[4];
#pragma unroll
    for (int n = 0; n < 4; ++n) {
        int oc = ocB * 64 + n * 16 + l15;
        bs[n] = (oc < 180) ? b2a[oc % 20] : 0.f;
    }
    __syncthreads();

    const unsigned short* hb = &sHalo[(lhi * 448 + w * 72 + l15) * 8];
    const unsigned short* wc = &sWc[lane * 8];

    f32x4 acc[4][4] = {};
    bf16x8 a0 = *(const bf16x8*)(hb), a1 = *(const bf16x8*)(hb + 128);
    bf16x8 a2 = *(const bf16x8*)(hb + 288), a3 = *(const bf16x8*)(hb + 416);
    bf16x8 c0 = *(const bf16x8*)(wc), c1 = *(const bf16x8*)(wc + 512);
    bf16x8 c2 = *(const bf16x8*)(wc + 1024), c3 = *(const bf16x8*)(wc + 1536);
    bf16x8 q0, q1, q2, q3, n0, n1, n2, n3;
#pragma unroll
    for (int t = 0; t < 25; ++t) {
        if (t < 24) {
            const int u = (((t + 1) / 5) * 36 + ((t + 1) % 5)) * 8;
            q0 = *(const bf16x8*)(hb + u);
            q1 = *(const bf16x8*)(hb + u + 128);
            q2 = *(const bf16x8*)(hb + u + 288);
            q3 = *(const bf16x8*)(hb + u + 416);
            const unsigned short* wn = wc + (t + 1) * 2048;
            n0 = *(const bf16x8*)(wn);
            n1 = *(const bf16x8*)(wn + 512);
            n2 = *(const bf16x8*)(wn + 1024);
            n3 = *(const bf16x8*)(wn + 1536);
        }
        MFMA16(a0, a1, a2, a3, c0, c1, c2, c3);
        if (t < 24) { a0 = q0; a1 = q1; a2 = q2; a3 = q3;
                      c0 = n0; c1 = n1; c2 = n2; c3 = n3; }
    }

#pragma unroll
    for (int n = 0; n < 4; ++n) {
        int oc = ocB * 64 + n * 16 + l15;
#pragma unroll
        for (int m = 0; m < 4; ++m) {
            int y = ty0 + w * 2 + (m >> 1);
            if (y >= 100) continue;
            int x0 = tx0 + (m & 1) * 16 + lhi * 4;
#pragma unroll
            for (int i = 0; i < 4; ++i) {
                int x = x0 + i;
                if (x >= 100) continue;
                Bn[((size_t)((b * 100 + y) * 100 + x)) * 192 + oc] =
                    f2bf(fmaxf(acc[m][n][i] + bs[n], 0.f));
            }
        }
    }
}

// ---------------- main MFMA conv: 32-oc tiles, halo-stationary A ----------------
__global__ __launch_bounds__(256, 2) void conv_mfma_kernel(
    const unsigned short* __restrict__ Pn, const unsigned short* __restrict__ Bn,
    const unsigned short* __restrict__ Wp, const float* __restrict__ b1,
    const float* __restrict__ b2b, float* __restrict__ out) {
    __shared__ __align__(16) unsigned short sHalo[4 * HSLOT * 8];  // 36,864 B

    const int tid  = threadIdx.x;
    const int lane = tid & 63, w = tid >> 6;
    const int l15  = lane & 15, lhi = lane >> 4;
    const int ocB  = blockIdx.x;          // 0..12 (fast: 13 ocB share one halo)
    const int pb   = blockIdx.y;          // 0..71
    const int b    = pb / 36;
    const int t36  = pb % 36;
    const int ty0  = (t36 / 3) * 8;
    const int tx0  = (t36 % 3) * 32;

    const int vA = (lhi * HSLOT + w * 72 + l15) * 8;

    auto stageA = [&](int cc) {  // Bn halo 12x36, wave w stages k-slot w
        for (int L2 = 0; L2 < 7; ++L2) {
            int p = L2 * 64 + lane;
            if (p >= 432) p = 0;
            int hy = (p * 58255) >> 21, hx = p - hy * 36;
            gload16(Bn + ((size_t)((b * 100 + ty0 + hy) * 100 + tx0 + hx)) * 192 +
                        cc * 32 + w * 8,
                    &sHalo[(w * HSLOT + L2 * 64) * 8]);
        }
    };
    auto stageB = [&](int seg) {  // Pn halo 16x36 (seg7 origin +5 cols)
        int cx = tx0 + (seg == 7 ? 5 : 0);
        for (int L2 = 0; L2 < 9; ++L2) {
            int p = L2 * 64 + lane;
            int hy = (p * 58255) >> 21, hx = p - hy * 36;
            int gx = cx + hx;
            gx = gx > 103 ? 103 : gx;     // clamped col never feeds valid output
            gload16(Pn + ((size_t)((b * 104 + ty0 + hy) * 104 + gx)) * 32 + w * 8,
                    &sHalo[(w * HSLOT + L2 * 64) * 8]);
        }
    };

    float bb2[2], bb1[2];
#pragma unroll
    for (int n = 0; n < 2; ++n) {
        int oc  = ocB * 32 + n * 16 + l15;
        int occ = oc < 400 ? oc : 399;
        bb2[n] = b2b[occ];
        bb1[n] = b1[occ];
    }

    f32x4 acc[4][2] = {};

    const unsigned short* wq = Wp + ocB * 1024 + lane * 8;

    auto tap = [&](int hoff) {
        const unsigned short* ha = &sHalo[vA + hoff];
        bf16x8 a0 = *(const bf16x8*)(ha);
        bf16x8 a1 = *(const bf16x8*)(ha + 128);
        bf16x8 a2 = *(const bf16x8*)(ha + 288);
        bf16x8 a3 = *(const bf16x8*)(ha + 416);
        bf16x8 c0 = *(const bf16x8*)(wq);
        bf16x8 c1 = *(const bf16x8*)(wq + 512);
        __builtin_amdgcn_s_setprio(1);
        acc[0][0] = __builtin_amdgcn_mfma_f32_16x16x32_bf16(a0, c0, acc[0][0], 0, 0, 0);
        acc[0][1] = __builtin_amdgcn_mfma_f32_16x16x32_bf16(a0, c1, acc[0][1], 0, 0, 0);
        acc[1][0] = __builtin_amdgcn_mfma_f32_16x16x32_bf16(a1, c0, acc[1][0], 0, 0, 0);
        acc[1][1] = __builtin_amdgcn_mfma_f32_16x16x32_bf16(a1, c1, acc[1][1], 0, 0, 0);
        acc[2][0] = __builtin_amdgcn_mfma_f32_16x16x32_bf16(a2, c0, acc[2][0], 0, 0, 0);
        acc[2][1] = __builtin_amdgcn_mfma_f32_16x16x32_bf16(a2, c1, acc[2][1], 0, 0, 0);
        acc[3][0] = __builtin_amdgcn_mfma_f32_16x16x32_bf16(a3, c0, acc[3][0], 0, 0, 0);
        acc[3][1] = __builtin_amdgcn_mfma_f32_16x16x32_bf16(a3, c1, acc[3][1], 0, 0, 0);
        __builtin_amdgcn_s_setprio(0);
        wq += WSTP;
    };

    // -------- phase A: 6 segments x 25 taps --------
    stageA(0);
    __syncthreads();
    for (int cc = 0; cc < 6; ++cc) {
#pragma unroll
        for (int t = 0; t < 25; ++t)
            tap(((t / 5) * 36 + (t % 5)) * 8);
        __syncthreads();
        if (cc < 5) {
            stageA(cc + 1);
            __syncthreads();
        }
    }

    // -------- mid: stage phase-B halo, relu(p2 + b2b) while it lands --------
    stageB(6);
#pragma unroll
    for (int m = 0; m < 4; ++m)
#pragma unroll
        for (int n = 0; n < 2; ++n)
#pragma unroll
            for (int i = 0; i < 4; ++i)
                acc[m][n][i] = fmaxf(acc[m][n][i] + bb2[n], 0.f);
    __syncthreads();

    // -------- phase B1: 45 taps (dy0..8, dx0..4) --------
#pragma unroll
    for (int t = 0; t < 45; ++t)
        tap(((t / 5) * 36 + (t % 5)) * 8);
    __syncthreads();
    stageB(7);
    __syncthreads();

    // -------- phase B2: 36 taps (dy0..8, dx5..8) --------
#pragma unroll
    for (int t = 0; t < 36; ++t)
        tap(((t >> 2) * 36 + (t & 3)) * 8);

    // -------- epilogue: (p1+p2+b1)/2, pixel-shuffled --------
#pragma unroll
    for (int n = 0; n < 2; ++n) {
        int oc = ocB * 32 + n * 16 + l15;
        if (oc >= 400) continue;
        float bv = bb1[n];
        int c25 = oc >> 4, r1 = (oc >> 2) & 3, r2 = oc & 3;
#pragma unroll
        for (int m = 0; m < 4; ++m) {
            int y  = ty0 + w * 2 + (m >> 1);
            int x0 = tx0 + (m & 1) * 16 + lhi * 4;
#pragma unroll
            for (int i = 0; i < 4; ++i) {
                out[((size_t)(b * 25 + c25) * 384 + y * 4 + r1) * 384 + (x0 + i) * 4 + r2] =
                    (acc[m][n][i] + bv) * 0.5f;
            }
        }
    }
}

extern "C" void kernel_launch(void* const* d_in, const int* in_sizes, int n_in,
                              void* d_out, int out_size, void* d_ws, size_t ws_size,
                              hipStream_t stream) {
    const float* pic = (const float*)d_in[0];
    const float* w1  = (const float*)d_in[1];
    const float* b1  = (const float*)d_in[2];
    const float* w2a = (const float*)d_in[3];
    const float* b2a = (const float*)d_in[4];
    const float* w2b = (const float*)d_in[5];
    const float* b2b = (const float*)d_in[6];
    float* out = (float*)d_out;

    char* ws = (char*)d_ws;
    unsigned short* Pn = (unsigned short*)(ws);             // 1,384,448 B
    unsigned short* Bn = (unsigned short*)(ws + 1384448);   // 7,680,000 B
    unsigned short* Wp = (unsigned short*)(ws + 9064448);   // 6,150,144 B

    pad_kernel<<<(NB * 104 * 104 + 255) / 256, 256, 0, stream>>>(pic, Pn);
    prep_w_kernel<<<((NWTOT / 8) + 255) / 256, 256, 0, stream>>>(w2b, w1, Wp);
    conv2a_mfma_kernel<<<dim3(104, 3), 256, 0, stream>>>(Pn, w2a, b2a, Bn);
    conv_mfma_kernel<<<dim3(13, 72), 256, 0, stream>>>(Pn, Bn, Wp, b1, b2b, out);
}

// Round 10
// 149.227 us; speedup vs baseline: 1.2801x; 1.2667x over previous
//
#include <hip/hip_runtime.h>
#include <hip/hip_bf16.h>

// ---------------------------------------------------------------------------
// DimNet via bf16 MFMA implicit GEMM.
//   Pn  = padded input  NHWC bf16 [2][104][104][32]
//   Bn  = relu(conv2a)  NHWC bf16 [2][100][100][192] (g' = uv*20+mc)
//   Wp  = packed main weights [231 steps][ocb7][frag4][lane64][8] bf16
//   Wc2 = packed conv2a weights [ocb6][tap25][slot128][8] bf16
// prep_fused: pad (85 blk) + w2b transpose (42) + w1 transpose (21) +
//   conv2a pack (6) — LDS-staged transposes: contiguous tap-run reads,
//   coalesced fragment writes (kills the 16x gather amplification).
// conv2a_mfma: 256 thr, 256px x 32oc, weights direct from Wc2 (L1-resident).
// conv_mfma: EXACT round-7 kernel (known 102us / 52% MfmaUtil).
// ---------------------------------------------------------------------------

typedef __attribute__((ext_vector_type(8))) unsigned short ushort8;
typedef __attribute__((ext_vector_type(8))) __bf16 bf16x8;
typedef __attribute__((ext_vector_type(4))) float f32x4;

#define NB 2
#define HSLOT 576             // cells per k-slot (16 rows x 36 cols)
#define HBUF (4 * HSLOT * 8)  // ushorts per halo buffer = 18432
#define WST 14336             // ushorts per step in packed weights (7*4*64*8)

static __device__ __forceinline__ unsigned short f2bf(float f) {
    __hip_bfloat16 h = __float2bfloat16(f);
    return *reinterpret_cast<unsigned short*>(&h);
}
static __device__ __forceinline__ void gload16(const unsigned short* g, unsigned short* l) {
    __builtin_amdgcn_global_load_lds(
        (const __attribute__((address_space(1))) unsigned int*)(const void*)g,
        (__attribute__((address_space(3))) unsigned int*)(void*)l, 16, 0, 0);
}

// ---------------- fused prep: pad + weight transposes + conv2a pack ----------------
__global__ __launch_bounds__(256) void prep_fused_kernel(
    const float* __restrict__ pic, const float* __restrict__ w1,
    const float* __restrict__ w2a, const float* __restrict__ w2b,
    unsigned short* __restrict__ Pn, unsigned short* __restrict__ Wp,
    unsigned short* __restrict__ Wc2) {
    __shared__ unsigned short sT[28544];  // stride-33 staging (57KB)
    const int blk = blockIdx.x;
    const int tid = threadIdx.x;

    if (blk < 85) {
        // ---- pad: pic -> Pn NHWC bf16 ----
        int idx = blk * 256 + tid;
        if (idx >= NB * 104 * 104) return;
        int x = idx % 104;
        int y = (idx / 104) % 104;
        int b = idx / (104 * 104);
        unsigned short vals[32];
        bool inter = (y >= 4 && y < 100 && x >= 4 && x < 100);
#pragma unroll
        for (int c = 0; c < 25; ++c) {
            float v = inter ? pic[((b * 25 + c) * 96 + (y - 4)) * 96 + (x - 4)] : 0.5f;
            vals[c] = f2bf(v);
        }
#pragma unroll
        for (int c = 25; c < 32; ++c) vals[c] = 0;
        ushort8* dst = (ushort8*)(Pn + idx * 32);
#pragma unroll
        for (int j = 0; j < 4; ++j) dst[j] = *(ushort8*)&vals[j * 8];
    } else if (blk < 127) {
        // ---- w2b transpose: block (ocB, cc), two 32-oc passes ----
        int b2 = blk - 85;
        int ocB = b2 % 7, cc = b2 / 7;
        for (int n32 = 0; n32 < 2; ++n32) {
            for (int j = 0; j < 4; ++j) {
                int p  = tid * 4 + j;
                int gl = p >> 5, ol = p & 31;
                int oc = ocB * 64 + n32 * 32 + ol;
                int gp = cc * 32 + gl;
                const float* src = nullptr;
                if (oc < 400 && gp < 180) {
                    int mc = gp % 20, uv = gp / 20;      // g' = uv*20 + mc
                    src = w2b + oc * 4500 + (mc * 9 + uv) * 25;
                }
#pragma unroll
                for (int tap = 0; tap < 25; ++tap)
                    sT[(gl * 25 + tap) * 33 + ol] = src ? f2bf(src[tap]) : (unsigned short)0;
            }
            __syncthreads();
            for (int i = 0; i < 13; ++i) {
                int sid = i * 256 + tid;
                if (sid < 3200) {
                    int tap = sid >> 7;
                    int r   = sid & 127;
                    int nb = r >> 6, lane = r & 63;
                    int kq = lane >> 4;
                    int olw = nb * 16 + (lane & 15);
                    unsigned short v8[8];
#pragma unroll
                    for (int e = 0; e < 8; ++e)
                        v8[e] = sT[((kq * 8 + e) * 25 + tap) * 33 + olw];
                    size_t d = (size_t)(cc * 25 + tap) * WST + ocB * 2048 +
                               (n32 * 2 + nb) * 512 + lane * 8;
                    *(ushort8*)(Wp + d) = *(ushort8*)v8;
                }
            }
            __syncthreads();
        }
    } else if (blk < 148) {
        // ---- w1 transpose: block (ocB, tap-third), two 32-oc passes ----
        int b3 = blk - 127;
        int ocB = b3 % 7, tt = b3 / 7;   // tt 0..2, 27 linear taps each
        for (int n32 = 0; n32 < 2; ++n32) {
            for (int j = 0; j < 4; ++j) {
                int p  = tid * 4 + j;
                int cl = p >> 5, ol = p & 31;
                int oc = ocB * 64 + n32 * 32 + ol;
                const float* src = (oc < 400 && cl < 25)
                                       ? (w1 + oc * 2025 + cl * 81 + tt * 27) : nullptr;
#pragma unroll
                for (int tl = 0; tl < 27; ++tl)
                    sT[(cl * 27 + tl) * 33 + ol] = src ? f2bf(src[tl]) : (unsigned short)0;
            }
            __syncthreads();
            for (int i = 0; i < 14; ++i) {
                int sid = i * 256 + tid;
                if (sid < 3456) {
                    int tl = sid >> 7;
                    int r  = sid & 127;
                    int nb = r >> 6, lane = r & 63;
                    int kq = lane >> 4;
                    int olw = nb * 16 + (lane & 15);
                    unsigned short v8[8];
#pragma unroll
                    for (int e = 0; e < 8; ++e)
                        v8[e] = sT[((kq * 8 + e) * 27 + tl) * 33 + olw];
                    int tap_lin = tt * 27 + tl;
                    int dy = tap_lin / 9, dx = tap_lin % 9;
                    int tp = (dx < 5) ? (dy * 5 + dx) : (45 + dy * 4 + (dx - 5));
                    size_t d = (size_t)(150 + tp) * WST + ocB * 2048 +
                               (n32 * 2 + nb) * 512 + lane * 8;
                    *(ushort8*)(Wp + d) = *(ushort8*)v8;
                }
            }
            __syncthreads();
        }
    } else if (blk < 154) {
        // ---- conv2a weight pack: block = ocB2 (32 oc), threads 0..127 ----
        int ocB2 = blk - 148;
        if (tid < 128) {
            int lane = tid & 63;
            int oc = ocB2 * 32 + (tid >> 6) * 16 + (lane & 15);
            int kb = (lane >> 4) * 8;
            int uv = oc / 20, mc = oc % 20;
            int u = uv / 3, v = uv % 3;
            const float* wb[8];
#pragma unroll
            for (int e = 0; e < 8; ++e) {
                int k  = kb + e;
                int c1 = k / 5, c2 = k % 5;
                int da1 = c1 - u, da2 = c2 - v;
                bool valid = (oc < 180) && ((unsigned)da1 < 3u) && ((unsigned)da2 < 3u);
                wb[e] = valid ? (w2a + mc * 225 + (da1 * 3 + da2) * 25) : (const float*)0;
            }
            for (int tap = 0; tap < 25; ++tap) {
                unsigned short fr[8];
#pragma unroll
                for (int e = 0; e < 8; ++e) fr[e] = wb[e] ? f2bf(wb[e][tap]) : (unsigned short)0;
                *(ushort8*)(Wc2 + ((size_t)(ocB2 * 25 + tap) * 128 + tid) * 8) = *(ushort8*)fr;
            }
        }
    }
}

// ---------------- conv2a via MFMA: 256px x 32oc, packed weights ----------------
__global__ __launch_bounds__(256) void conv2a_mfma_kernel(
    const unsigned short* __restrict__ Pn, const unsigned short* __restrict__ Wc2,
    const float* __restrict__ b2a, unsigned short* __restrict__ Bn) {
    __shared__ __align__(16) unsigned short sHalo[4 * 448 * 8];  // 28,672 B

    const int tid  = threadIdx.x;
    const int lane = tid & 63, w = tid >> 6;
    const int l15  = lane & 15, lhi = lane >> 4;
    const int gx0  = blockIdx.x;          // 0..103
    const int b    = gx0 / 52, t52 = gx0 % 52;
    const int ty0  = (t52 >> 2) * 8;
    const int tx0  = (t52 & 3) * 32;
    const int ocB  = blockIdx.y;          // 0..5 (32 oc each)

    for (int L2 = 0; L2 < 7; ++L2) {
        int p = L2 * 64 + lane;
        if (p >= 432) p = 0;
        int hy = (p * 58255) >> 21, hx = p - hy * 36;
        int gy = ty0 + hy; gy = gy > 103 ? 103 : gy;
        int gx = tx0 + hx; gx = gx > 103 ? 103 : gx;
        gload16(Pn + ((size_t)((b * 104 + gy) * 104 + gx)) * 32 + w * 8,
                &sHalo[(w * 448 + L2 * 64) * 8]);
    }
    float bs[2];
#pragma unroll
    for (int n = 0; n < 2; ++n) {
        int oc = ocB * 32 + n * 16 + l15;
        bs[n] = (oc < 180) ? b2a[oc % 20] : 0.f;
    }
    __syncthreads();

    const unsigned short* hb = &sHalo[(lhi * 448 + w * 72 + l15) * 8];
    const unsigned short* wq = Wc2 + (size_t)ocB * 25600 + lane * 8;

    f32x4 acc[4][2] = {};
#pragma unroll
    for (int t = 0; t < 25; ++t) {
        const int u = ((t / 5) * 36 + (t % 5)) * 8;
        bf16x8 a0 = *(const bf16x8*)(hb + u);
        bf16x8 a1 = *(const bf16x8*)(hb + u + 128);
        bf16x8 a2 = *(const bf16x8*)(hb + u + 288);
        bf16x8 a3 = *(const bf16x8*)(hb + u + 416);
        bf16x8 c0 = *(const bf16x8*)(wq);
        bf16x8 c1 = *(const bf16x8*)(wq + 512);
        __builtin_amdgcn_s_setprio(1);
        acc[0][0] = __builtin_amdgcn_mfma_f32_16x16x32_bf16(a0, c0, acc[0][0], 0, 0, 0);
        acc[0][1] = __builtin_amdgcn_mfma_f32_16x16x32_bf16(a0, c1, acc[0][1], 0, 0, 0);
        acc[1][0] = __builtin_amdgcn_mfma_f32_16x16x32_bf16(a1, c0, acc[1][0], 0, 0, 0);
        acc[1][1] = __builtin_amdgcn_mfma_f32_16x16x32_bf16(a1, c1, acc[1][1], 0, 0, 0);
        acc[2][0] = __builtin_amdgcn_mfma_f32_16x16x32_bf16(a2, c0, acc[2][0], 0, 0, 0);
        acc[2][1] = __builtin_amdgcn_mfma_f32_16x16x32_bf16(a2, c1, acc[2][1], 0, 0, 0);
        acc[3][0] = __builtin_amdgcn_mfma_f32_16x16x32_bf16(a3, c0, acc[3][0], 0, 0, 0);
        acc[3][1] = __builtin_amdgcn_mfma_f32_16x16x32_bf16(a3, c1, acc[3][1], 0, 0, 0);
        __builtin_amdgcn_s_setprio(0);
        wq += 1024;
    }

#pragma unroll
    for (int n = 0; n < 2; ++n) {
        int oc = ocB * 32 + n * 16 + l15;
#pragma unroll
        for (int m = 0; m < 4; ++m) {
            int y = ty0 + w * 2 + (m >> 1);
            if (y >= 100) continue;
            int x0 = tx0 + (m & 1) * 16 + lhi * 4;
#pragma unroll
            for (int i = 0; i < 4; ++i) {
                int x = x0 + i;
                if (x >= 100) continue;
                Bn[((size_t)((b * 100 + y) * 100 + x)) * 192 + oc] =
                    f2bf(fmaxf(acc[m][n][i] + bs[n], 0.f));
            }
        }
    }
}

// ---------------- main MFMA conv: EXACT round-7 kernel ----------------
#define MFMA16(A0, A1, A2, A3, B0, B1, B2, B3)                                          \
    {                                                                                   \
        __builtin_amdgcn_s_setprio(1);                                                  \
        acc[0][0] = __builtin_amdgcn_mfma_f32_16x16x32_bf16(A0, B0, acc[0][0], 0, 0, 0);\
        acc[0][1] = __builtin_amdgcn_mfma_f32_16x16x32_bf16(A0, B1, acc[0][1], 0, 0, 0);\
        acc[0][2] = __builtin_amdgcn_mfma_f32_16x16x32_bf16(A0, B2, acc[0][2], 0, 0, 0);\
        acc[0][3] = __builtin_amdgcn_mfma_f32_16x16x32_bf16(A0, B3, acc[0][3], 0, 0, 0);\
        acc[1][0] = __builtin_amdgcn_mfma_f32_16x16x32_bf16(A1, B0, acc[1][0], 0, 0, 0);\
        acc[1][1] = __builtin_amdgcn_mfma_f32_16x16x32_bf16(A1, B1, acc[1][1], 0, 0, 0);\
        acc[1][2] = __builtin_amdgcn_mfma_f32_16x16x32_bf16(A1, B2, acc[1][2], 0, 0, 0);\
        acc[1][3] = __builtin_amdgcn_mfma_f32_16x16x32_bf16(A1, B3, acc[1][3], 0, 0, 0);\
        acc[2][0] = __builtin_amdgcn_mfma_f32_16x16x32_bf16(A2, B0, acc[2][0], 0, 0, 0);\
        acc[2][1] = __builtin_amdgcn_mfma_f32_16x16x32_bf16(A2, B1, acc[2][1], 0, 0, 0);\
        acc[2][2] = __builtin_amdgcn_mfma_f32_16x16x32_bf16(A2, B2, acc[2][2], 0, 0, 0);\
        acc[2][3] = __builtin_amdgcn_mfma_f32_16x16x32_bf16(A2, B3, acc[2][3], 0, 0, 0);\
        acc[3][0] = __builtin_amdgcn_mfma_f32_16x16x32_bf16(A3, B0, acc[3][0], 0, 0, 0);\
        acc[3][1] = __builtin_amdgcn_mfma_f32_16x16x32_bf16(A3, B1, acc[3][1], 0, 0, 0);\
        acc[3][2] = __builtin_amdgcn_mfma_f32_16x16x32_bf16(A3, B2, acc[3][2], 0, 0, 0);\
        acc[3][3] = __builtin_amdgcn_mfma_f32_16x16x32_bf16(A3, B3, acc[3][3], 0, 0, 0);\
        __builtin_amdgcn_s_setprio(0);                                                  \
    }

__global__ __launch_bounds__(256, 2) void conv_mfma_kernel(
    const unsigned short* __restrict__ Pn, const unsigned short* __restrict__ Bn,
    const unsigned short* __restrict__ Wp, const float* __restrict__ b1,
    const float* __restrict__ b2b, float* __restrict__ out) {
    __shared__ __align__(16) unsigned short sHalo[2 * HBUF];  // 73,728 B

    const int tid  = threadIdx.x;
    const int lane = tid & 63, w = tid >> 6;
    const int l15  = lane & 15, lhi = lane >> 4;
    const int ocB  = blockIdx.y;
    const int pb   = blockIdx.x;
    const int b    = pb / 36;
    const int t36  = pb % 36;
    const int ty0  = (t36 / 3) * 8;
    const int tx0  = (t36 % 3) * 32;

    const int vA = (lhi * HSLOT + w * 72 + l15) * 8;

    auto stageA = [&](int cc, int par) {
        unsigned short* dst0 = &sHalo[par * HBUF + w * HSLOT * 8];
        for (int L2 = 0; L2 < 7; ++L2) {
            int p = L2 * 64 + lane;
            if (p >= 432) p = 0;
            int hy = (p * 58255) >> 21, hx = p - hy * 36;
            gload16(Bn + ((size_t)((b * 100 + ty0 + hy) * 100 + tx0 + hx)) * 192 +
                        cc * 32 + w * 8,
                    dst0 + L2 * 512);
        }
    };
    auto stageB = [&](int seg, int par) {
        int cx = tx0 + (seg == 7 ? 5 : 0);
        unsigned short* dst0 = &sHalo[par * HBUF + w * HSLOT * 8];
        for (int L2 = 0; L2 < 9; ++L2) {
            int p = L2 * 64 + lane;
            int hy = (p * 58255) >> 21, hx = p - hy * 36;
            int gx = cx + hx;
            gx = gx > 103 ? 103 : gx;
            gload16(Pn + ((size_t)((b * 104 + ty0 + hy) * 104 + gx)) * 32 + w * 8,
                    dst0 + L2 * 512);
        }
    };

    float bb2[4], bb1[4];
#pragma unroll
    for (int n = 0; n < 4; ++n) {
        int oc  = ocB * 64 + n * 16 + l15;
        int occ = oc < 400 ? oc : 399;
        bb2[n] = b2b[occ];
        bb1[n] = b1[occ];
    }

    const unsigned short* wq = Wp + ocB * 2048 + lane * 8;
    bf16x8 c0 = *(const bf16x8*)(wq);
    bf16x8 c1 = *(const bf16x8*)(wq + 512);
    bf16x8 c2 = *(const bf16x8*)(wq + 1024);
    bf16x8 c3 = *(const bf16x8*)(wq + 1536);
    stageA(0, 0);
    __syncthreads();

    f32x4 acc[4][4] = {};
    bf16x8 a0, a1, a2, a3, q0, q1, q2, q3, n0, n1, n2, n3;

    for (int cc = 0; cc < 6; ++cc) {
        const unsigned short* hb = &sHalo[(cc & 1) * HBUF + vA];
        a0 = *(const bf16x8*)(hb);
        a1 = *(const bf16x8*)(hb + 128);
        a2 = *(const bf16x8*)(hb + 288);
        a3 = *(const bf16x8*)(hb + 416);
        if (cc < 5) stageA(cc + 1, (cc + 1) & 1);
        else        stageB(6, 0);
#pragma unroll
        for (int t = 0; t < 25; ++t) {
            wq += WST;
            n0 = *(const bf16x8*)(wq);
            n1 = *(const bf16x8*)(wq + 512);
            n2 = *(const bf16x8*)(wq + 1024);
            n3 = *(const bf16x8*)(wq + 1536);
            if (t < 24) {
                const int u = (((t + 1) / 5) * 36 + ((t + 1) % 5)) * 8;
                q0 = *(const bf16x8*)(hb + u);
                q1 = *(const bf16x8*)(hb + u + 128);
                q2 = *(const bf16x8*)(hb + u + 288);
                q3 = *(const bf16x8*)(hb + u + 416);
            }
            MFMA16(a0, a1, a2, a3, c0, c1, c2, c3);
            c0 = n0; c1 = n1; c2 = n2; c3 = n3;
            if (t < 24) { a0 = q0; a1 = q1; a2 = q2; a3 = q3; }
        }
        if (cc == 5) {
#pragma unroll
            for (int m = 0; m < 4; ++m)
#pragma unroll
                for (int n = 0; n < 4; ++n)
#pragma unroll
                    for (int i = 0; i < 4; ++i)
                        acc[m][n][i] = fmaxf(acc[m][n][i] + bb2[n], 0.f);
        }
        asm volatile("s_waitcnt vmcnt(4)" ::: "memory");
        asm volatile("s_barrier" ::: "memory");
    }

    {
        const unsigned short* hb = &sHalo[vA];
        a0 = *(const bf16x8*)(hb);
        a1 = *(const bf16x8*)(hb + 128);
        a2 = *(const bf16x8*)(hb + 288);
        a3 = *(const bf16x8*)(hb + 416);
        stageB(7, 1);
#pragma unroll
        for (int t = 0; t < 45; ++t) {
            wq += WST;
            n0 = *(const bf16x8*)(wq);
            n1 = *(const bf16x8*)(wq + 512);
            n2 = *(const bf16x8*)(wq + 1024);
            n3 = *(const bf16x8*)(wq + 1536);
            if (t < 44) {
                const int u = (((t + 1) / 5) * 36 + ((t + 1) % 5)) * 8;
                q0 = *(const bf16x8*)(hb + u);
                q1 = *(const bf16x8*)(hb + u + 128);
                q2 = *(const bf16x8*)(hb + u + 288);
                q3 = *(const bf16x8*)(hb + u + 416);
            }
            MFMA16(a0, a1, a2, a3, c0, c1, c2, c3);
            c0 = n0; c1 = n1; c2 = n2; c3 = n3;
            if (t < 44) { a0 = q0; a1 = q1; a2 = q2; a3 = q3; }
        }
        asm volatile("s_waitcnt vmcnt(4)" ::: "memory");
        asm volatile("s_barrier" ::: "memory");
    }

    {
        const unsigned short* hb = &sHalo[HBUF + vA];
        a0 = *(const bf16x8*)(hb);
        a1 = *(const bf16x8*)(hb + 128);
        a2 = *(const bf16x8*)(hb + 288);
        a3 = *(const bf16x8*)(hb + 416);
#pragma unroll
        for (int t = 0; t < 36; ++t) {
            if (t < 35) {
                wq += WST;
                n0 = *(const bf16x8*)(wq);
                n1 = *(const bf16x8*)(wq + 512);
                n2 = *(const bf16x8*)(wq + 1024);
                n3 = *(const bf16x8*)(wq + 1536);
                const int u = (((t + 1) / 4) * 36 + ((t + 1) % 4)) * 8;
                q0 = *(const bf16x8*)(hb + u);
                q1 = *(const bf16x8*)(hb + u + 128);
                q2 = *(const bf16x8*)(hb + u + 288);
                q3 = *(const bf16x8*)(hb + u + 416);
            }
            MFMA16(a0, a1, a2, a3, c0, c1, c2, c3);
            if (t < 35) { a0 = q0; a1 = q1; a2 = q2; a3 = q3;
                          c0 = n0; c1 = n1; c2 = n2; c3 = n3; }
        }
    }

#pragma unroll
    for (int n = 0; n < 4; ++n) {
        int oc = ocB * 64 + n * 16 + l15;
        if (oc >= 400) continue;
        float bv = bb1[n];
        int c25 = oc >> 4, r1 = (oc >> 2) & 3, r2 = oc & 3;
#pragma unroll
        for (int m = 0; m < 4; ++m) {
            int y  = ty0 + w * 2 + (m >> 1);
            int x0 = tx0 + (m & 1) * 16 + lhi * 4;
#pragma unroll
            for (int i = 0; i < 4; ++i) {
                out[((size_t)(b * 25 + c25) * 384 + y * 4 + r1) * 384 + (x0 + i) * 4 + r2] =
                    (acc[m][n][i] + bv) * 0.5f;
            }
        }
    }
}

extern "C" void kernel_launch(void* const* d_in, const int* in_sizes, int n_in,
                              void* d_out, int out_size, void* d_ws, size_t ws_size,
                              hipStream_t stream) {
    const float* pic = (const float*)d_in[0];
    const float* w1  = (const float*)d_in[1];
    const float* b1  = (const float*)d_in[2];
    const float* w2a = (const float*)d_in[3];
    const float* b2a = (const float*)d_in[4];
    const float* w2b = (const float*)d_in[5];
    const float* b2b = (const float*)d_in[6];
    float* out = (float*)d_out;

    char* ws = (char*)d_ws;
    unsigned short* Pn  = (unsigned short*)(ws);              // 1,384,448 B
    unsigned short* Bn  = (unsigned short*)(ws + 1384448);    // 7,680,000 B
    unsigned short* Wp  = (unsigned short*)(ws + 9064448);    // 6,623,232 B
    unsigned short* Wc2 = (unsigned short*)(ws + 15687680);   //   307,200 B

    prep_fused_kernel<<<154, 256, 0, stream>>>(pic, w1, w2a, w2b, Pn, Wp, Wc2);
    conv2a_mfma_kernel<<<dim3(104, 6), 256, 0, stream>>>(Pn, Wc2, b2a, Bn);
    conv_mfma_kernel<<<dim3(72, 7), 256, 0, stream>>>(Pn, Bn, Wp, b1, b2b, out);
}